// Round 1
// baseline (1406.331 us; speedup 1.0000x reference)
//
#include <hip/hip_runtime.h>

typedef _Float16 f16;
typedef f16 f16x4 __attribute__((ext_vector_type(4)));
typedef f16 f16x8 __attribute__((ext_vector_type(8)));
typedef float f32x4 __attribute__((ext_vector_type(4)));

#define BATCH 32
#define CCH   512
#define HWSZ  4096
#define PERB  (CCH*HWSZ)   // 2097152 elements per batch plane
#define EPB   (CCH*CCH)    // 262144 elements per (b,head) energy plane

// ---------------- weight convert fp32 -> fp16 ----------------
__global__ __launch_bounds__(256) void wconv_k(
    const float* __restrict__ Wq, const float* __restrict__ Wk,
    const float* __restrict__ Wv, f16* __restrict__ Wqk, f16* __restrict__ Wvh)
{
  const int idx = (blockIdx.x*256 + threadIdx.x)*4;   // 256 blocks * 256 thr * 4 = 262144 exact
  float4 q = *(const float4*)(Wq+idx);
  float4 k = *(const float4*)(Wk+idx);
  float4 v = *(const float4*)(Wv+idx);
  f16x4 oq = {(f16)q.x,(f16)q.y,(f16)q.z,(f16)q.w};
  f16x4 ok = {(f16)k.x,(f16)k.y,(f16)k.z,(f16)k.w};
  f16x4 ov = {(f16)v.x,(f16)v.y,(f16)v.z,(f16)v.w};
  *(f16x4*)(Wqk+idx)      = oq;
  *(f16x4*)(Wqk+EPB+idx)  = ok;   // rows 512..1023 = Wk
  *(f16x4*)(Wvh+idx)      = ov;
}

// ---------------- transpose x (b,c,hw) fp32 -> Xt (b,hw,c) fp16 ----------------
__global__ __launch_bounds__(256) void transpose_k(
    const float* __restrict__ x, f16* __restrict__ Xt)
{
  __shared__ f16 tile[64][80];   // pad to 80 (160B rows) keeps 16B-aligned vector LDS ops
  const int s0 = blockIdx.x*64, c0 = blockIdx.y*64, b = blockIdx.z;
  const int t = threadIdx.x;
  const int r = t>>2, cs = (t&3)*16;
  const float* src = x + (size_t)b*PERB + (size_t)(c0+r)*HWSZ + s0 + cs;
  float4 v0 = *(const float4*)src;
  float4 v1 = *(const float4*)(src+4);
  float4 v2 = *(const float4*)(src+8);
  float4 v3 = *(const float4*)(src+12);
  f16x8 p0 = {(f16)v0.x,(f16)v0.y,(f16)v0.z,(f16)v0.w,(f16)v1.x,(f16)v1.y,(f16)v1.z,(f16)v1.w};
  f16x8 p1 = {(f16)v2.x,(f16)v2.y,(f16)v2.z,(f16)v2.w,(f16)v3.x,(f16)v3.y,(f16)v3.z,(f16)v3.w};
  *(f16x8*)&tile[r][cs]   = p0;   // tile[c_local][s_local]
  *(f16x8*)&tile[r][cs+8] = p1;
  __syncthreads();
  f16x8 o0, o1;
  #pragma unroll
  for (int k=0;k<8;k++){ o0[k]=tile[cs+k][r]; o1[k]=tile[cs+8+k][r]; }
  f16* dst = Xt + (size_t)b*PERB + (size_t)(s0+r)*CCH + c0 + cs;
  *(f16x8*)dst     = o0;
  *(f16x8*)(dst+8) = o1;
}

// ---------------- row softmax: E (65536 x 512) fp32 -> P fp16 ----------------
__global__ __launch_bounds__(256) void softmax_k(
    const float* __restrict__ E, f16* __restrict__ P)
{
  const int wv = threadIdx.x>>6, lane = threadIdx.x&63;
  const size_t row = (size_t)blockIdx.x*4 + wv;
  const float* e = E + row*CCH + lane*8;
  float4 a = *(const float4*)e;
  float4 b = *(const float4*)(e+4);
  float v[8] = {a.x,a.y,a.z,a.w,b.x,b.y,b.z,b.w};
  float m = v[0];
  #pragma unroll
  for (int k=1;k<8;k++) m = fmaxf(m, v[k]);
  #pragma unroll
  for (int off=32; off; off>>=1) m = fmaxf(m, __shfl_xor(m, off));
  float s = 0.f;
  #pragma unroll
  for (int k=0;k<8;k++){ v[k] = __expf(v[k]-m); s += v[k]; }
  #pragma unroll
  for (int off=32; off; off>>=1) s += __shfl_xor(s, off);
  const float inv = 1.0f / s;
  f16x8 o;
  #pragma unroll
  for (int k=0;k<8;k++) o[k] = (f16)(v[k]*inv);
  *(f16x8*)(P + row*CCH + lane*8) = o;
}

// ---------------- generic 128x128 A * B^T GEMM (m97-style, reg-staged LDS) ----
// MODE 0: QK-proj  A=Wqk(1024x512)        B=Xt[b](4096x512)      -> Q,K fp16 (+row bias)
// MODE 1: V-proj   A=Xt[b](4096x512)      B=Wv(512x512)          -> Vt fp16 (+col bias)
// MODE 2: energy   A=Q[b,h](512x1024 ld4096) B=K[b,h]            -> E fp32
// MODE 3: PV       A=P[bh](512x512)       B=Vt[b,h](1024x512)    -> out = gamma*acc + x
template<int MODE>
__global__ __launch_bounds__(256) void gemm_k(
    const f16* __restrict__ Aroot, const f16* __restrict__ Broot,
    void* __restrict__ out0, void* __restrict__ out1,
    const float* __restrict__ bias0, const float* __restrict__ bias1,
    const float* __restrict__ xin, const float* __restrict__ gam)
{
  constexpr int K   = (MODE==2) ? 1024 : 512;
  constexpr int LDA = (MODE==2) ? 4096 : 512;
  constexpr int LDB = (MODE==2) ? 4096 : 512;
  constexpr int NT  = K/32;

  const int t  = threadIdx.x;
  const int z  = blockIdx.z;
  const int m0 = blockIdx.y*128, n0 = blockIdx.x*128;

  const f16* Ap; const f16* Bp;
  if constexpr (MODE==0)      { Ap = Aroot;                    Bp = Broot + (size_t)z*PERB; }
  else if constexpr (MODE==1) { Ap = Aroot + (size_t)z*PERB;   Bp = Broot; }
  else if constexpr (MODE==2) { const int b=z>>2, h=z&3;
                                Ap = Aroot + (size_t)b*PERB + h*1024;
                                Bp = Broot + (size_t)b*PERB + h*1024; }
  else                        { const int b=z>>2, h=z&3;
                                Ap = Aroot + (size_t)z*EPB;
                                Bp = Broot + (size_t)b*PERB + (size_t)h*1024*512; }

  __shared__ f16 sA[128*32];
  __shared__ f16 sB[128*32];

  const int sr = t>>2, sc = (t&3)*8;

  f16x8 ra0, ra1, rb0, rb1;
  auto LOADT = [&](int KS) {
    const size_t ko = (size_t)KS + sc;
    ra0 = *(const f16x8*)(Ap + (size_t)(m0+sr)   *LDA + ko);
    ra1 = *(const f16x8*)(Ap + (size_t)(m0+64+sr)*LDA + ko);
    rb0 = *(const f16x8*)(Bp + (size_t)(n0+sr)   *LDB + ko);
    rb1 = *(const f16x8*)(Bp + (size_t)(n0+64+sr)*LDB + ko);
  };

  LOADT(0);

  const f32x4 zero = {0.f,0.f,0.f,0.f};
  f32x4 acc[4][4];
  #pragma unroll
  for (int i=0;i<4;i++)
    #pragma unroll
    for (int j=0;j<4;j++) acc[i][j] = zero;

  const int wv = t>>6, lane = t&63;
  const int wm = (wv>>1)*64, wn = (wv&1)*64;
  const int lrow = lane&15, lk = (lane>>4)*8;

  for (int ks=0; ks<NT; ++ks) {
    __syncthreads();                       // LDS consumers of previous tile done
    *(f16x8*)&sA[ sr    *32 + sc] = ra0;
    *(f16x8*)&sA[(64+sr)*32 + sc] = ra1;
    *(f16x8*)&sB[ sr    *32 + sc] = rb0;
    *(f16x8*)&sB[(64+sr)*32 + sc] = rb1;
    __syncthreads();
    if (ks+1 < NT) LOADT((ks+1)*32);       // next-tile loads hide under compute
    f16x8 af[4], bf[4];
    #pragma unroll
    for (int i=0;i<4;i++) af[i] = *(const f16x8*)&sA[(wm + i*16 + lrow)*32 + lk];
    #pragma unroll
    for (int j=0;j<4;j++) bf[j] = *(const f16x8*)&sB[(wn + j*16 + lrow)*32 + lk];
    #pragma unroll
    for (int i=0;i<4;i++)
      #pragma unroll
      for (int j=0;j<4;j++)
        acc[i][j] = __builtin_amdgcn_mfma_f32_16x16x32_f16(af[i], bf[j], acc[i][j], 0,0,0);
  }

  // C/D layout (m89-verified): col = lane&15, row = (lane>>4)*4 + reg
  const int rbase = m0 + wm + (lane>>4)*4;
  #pragma unroll
  for (int i=0;i<4;i++) {
    const int row = rbase + i*16;
    #pragma unroll
    for (int j=0;j<4;j++) {
      const int col = n0 + wn + j*16 + lrow;
      f32x4 v = acc[i][j];
      #pragma unroll
      for (int r=0;r<4;r++) {
        const int rr = row + r;
        if constexpr (MODE==0) {
          if (rr < 512)
            ((f16*)out0)[(size_t)z*PERB + (size_t)rr*HWSZ + col]        = (f16)(v[r] + bias0[rr]);
          else
            ((f16*)out1)[(size_t)z*PERB + (size_t)(rr-512)*HWSZ + col]  = (f16)(v[r] + bias1[rr-512]);
        } else if constexpr (MODE==1) {
          ((f16*)out0)[(size_t)z*PERB + (size_t)rr*CCH + col] = (f16)(v[r] + bias0[col]);
        } else if constexpr (MODE==2) {
          ((float*)out0)[(size_t)z*EPB + (size_t)rr*CCH + col] = v[r];
        } else {
          const int b = z>>2, h = z&3;
          const size_t idx = (size_t)b*PERB + (size_t)rr*HWSZ + h*1024 + col;
          ((float*)out0)[idx] = gam[0]*v[r] + xin[idx];
        }
      }
    }
  }
}

extern "C" void kernel_launch(void* const* d_in, const int* in_sizes, int n_in,
                              void* d_out, int out_size, void* d_ws, size_t ws_size,
                              hipStream_t stream)
{
  const float* x  = (const float*)d_in[0];
  const float* Wq = (const float*)d_in[1];
  const float* bq = (const float*)d_in[2];
  const float* Wk = (const float*)d_in[3];
  const float* bk = (const float*)d_in[4];
  const float* Wv = (const float*)d_in[5];
  const float* bv = (const float*)d_in[6];
  const float* gm = (const float*)d_in[7];

  // ws layout (~258 MiB): Qb[134M] | Kb[134M] | Wqk[1M] | Wvh[0.5M]
  // aliases by lifetime: P -> Qb (Q dead after energy); Vt -> Kb (K dead after energy)
  char* ws  = (char*)d_ws;
  f16* Qb   = (f16*)ws;
  f16* Kb   = (f16*)(ws + 134217728ull);
  f16* Wqk  = (f16*)(ws + 268435456ull);
  f16* Wvh  = Wqk + 1024*512;
  f16* Pb   = Qb;
  f16* Vt   = Kb;
  // d_out doubles as scratch until the final PV epilogue overwrites all of it:
  float* E  = (float*)d_out;                              // [0, 134M)  energy fp32
  f16*  Xt  = (f16*)((char*)d_out + 134217728ull);        // [134M,268M) x^T fp16
  float* out = (float*)d_out;

  wconv_k    <<<256, 256, 0, stream>>>(Wq, Wk, Wv, Wqk, Wvh);
  transpose_k<<<dim3(64,8,32),  256, 0, stream>>>(x, Xt);
  gemm_k<0>  <<<dim3(32,8,32),  256, 0, stream>>>(Wqk, Xt, Qb, Kb, bq, bk, nullptr, nullptr);
  gemm_k<2>  <<<dim3(4,4,128),  256, 0, stream>>>(Qb, Kb, E, nullptr, nullptr, nullptr, nullptr, nullptr);
  gemm_k<1>  <<<dim3(4,32,32),  256, 0, stream>>>(Xt, Wvh, Vt, nullptr, bv, nullptr, nullptr, nullptr);
  softmax_k  <<<16384, 256, 0, stream>>>(E, Pb);
  gemm_k<3>  <<<dim3(8,4,128),  256, 0, stream>>>(Pb, Vt, out, nullptr, nullptr, nullptr, x, gm);
}

// Round 2
// 1261.639 us; speedup vs baseline: 1.1147x; 1.1147x over previous
//
#include <hip/hip_runtime.h>

typedef _Float16 f16;
typedef f16 f16x4 __attribute__((ext_vector_type(4)));
typedef f16 f16x8 __attribute__((ext_vector_type(8)));
typedef float f32x4 __attribute__((ext_vector_type(4)));

#define BATCH 32
#define CCH   512
#define HWSZ  4096
#define PERB  (CCH*HWSZ)   // 2097152 elements per batch plane
#define EPB   (CCH*CCH)    // 262144 elements per (b,head) energy plane

// global -> LDS direct DMA, 16B per lane. LDS dest must be wave-uniform base;
// HW writes base + lane*16 (linear). Our [rows][32 f16] layout is exactly that.
typedef __attribute__((address_space(3))) uint32_t lds_u32;
typedef const __attribute__((address_space(1))) uint32_t glb_u32;
__device__ __forceinline__ void gload16(const void* g, void* l) {
  __builtin_amdgcn_global_load_lds((glb_u32*)(uintptr_t)g, (lds_u32*)(uintptr_t)l, 16, 0, 0);
}

// ---------------- weight convert fp32 -> fp16 ----------------
__global__ __launch_bounds__(256) void wconv_k(
    const float* __restrict__ Wq, const float* __restrict__ Wk,
    const float* __restrict__ Wv, f16* __restrict__ Wqk, f16* __restrict__ Wvh)
{
  const int idx = (blockIdx.x*256 + threadIdx.x)*4;   // 256*256*4 = 262144 exact
  float4 q = *(const float4*)(Wq+idx);
  float4 k = *(const float4*)(Wk+idx);
  float4 v = *(const float4*)(Wv+idx);
  f16x4 oq = {(f16)q.x,(f16)q.y,(f16)q.z,(f16)q.w};
  f16x4 ok = {(f16)k.x,(f16)k.y,(f16)k.z,(f16)k.w};
  f16x4 ov = {(f16)v.x,(f16)v.y,(f16)v.z,(f16)v.w};
  *(f16x4*)(Wqk+idx)      = oq;
  *(f16x4*)(Wqk+EPB+idx)  = ok;   // rows 512..1023 = Wk
  *(f16x4*)(Wvh+idx)      = ov;
}

// ---------------- transpose x (b,c,hw) fp32 -> Xt (b,hw,c) fp16 ----------------
__global__ __launch_bounds__(256) void transpose_k(
    const float* __restrict__ x, f16* __restrict__ Xt)
{
  __shared__ f16 tile[64][80];
  const int s0 = blockIdx.x*64, c0 = blockIdx.y*64, b = blockIdx.z;
  const int t = threadIdx.x;
  const int r = t>>2, cs = (t&3)*16;
  const float* src = x + (size_t)b*PERB + (size_t)(c0+r)*HWSZ + s0 + cs;
  float4 v0 = *(const float4*)src;
  float4 v1 = *(const float4*)(src+4);
  float4 v2 = *(const float4*)(src+8);
  float4 v3 = *(const float4*)(src+12);
  f16x8 p0 = {(f16)v0.x,(f16)v0.y,(f16)v0.z,(f16)v0.w,(f16)v1.x,(f16)v1.y,(f16)v1.z,(f16)v1.w};
  f16x8 p1 = {(f16)v2.x,(f16)v2.y,(f16)v2.z,(f16)v2.w,(f16)v3.x,(f16)v3.y,(f16)v3.z,(f16)v3.w};
  *(f16x8*)&tile[r][cs]   = p0;
  *(f16x8*)&tile[r][cs+8] = p1;
  __syncthreads();
  f16x8 o0, o1;
  #pragma unroll
  for (int k=0;k<8;k++){ o0[k]=tile[cs+k][r]; o1[k]=tile[cs+8+k][r]; }
  f16* dst = Xt + (size_t)b*PERB + (size_t)(s0+r)*CCH + c0 + cs;
  *(f16x8*)dst     = o0;
  *(f16x8*)(dst+8) = o1;
}

// ---------------- row softmax: E (65536 x 512) fp32 -> P fp16 ----------------
__global__ __launch_bounds__(256) void softmax_k(
    const float* __restrict__ E, f16* __restrict__ P)
{
  const int wv = threadIdx.x>>6, lane = threadIdx.x&63;
  const size_t row = (size_t)blockIdx.x*4 + wv;
  const float* e = E + row*CCH + lane*8;
  float4 a = *(const float4*)e;
  float4 b = *(const float4*)(e+4);
  float v[8] = {a.x,a.y,a.z,a.w,b.x,b.y,b.z,b.w};
  float m = v[0];
  #pragma unroll
  for (int k=1;k<8;k++) m = fmaxf(m, v[k]);
  #pragma unroll
  for (int off=32; off; off>>=1) m = fmaxf(m, __shfl_xor(m, off));
  float s = 0.f;
  #pragma unroll
  for (int k=0;k<8;k++){ v[k] = __expf(v[k]-m); s += v[k]; }
  #pragma unroll
  for (int off=32; off; off>>=1) s += __shfl_xor(s, off);
  const float inv = 1.0f / s;
  f16x8 o;
  #pragma unroll
  for (int k=0;k<8;k++) o[k] = (f16)(v[k]*inv);
  *(f16x8*)(P + row*CCH + lane*8) = o;
}

// ---------------- generic 128x128 A * B^T GEMM (global_load_lds staging) ----
// MODE 0: QK-proj  A=Wqk(1024x512)           B=Xt[b](4096x512)  -> Q,K fp16 (+row bias)
// MODE 1: V-proj   A=Xt[b](4096x512)         B=Wv(512x512)      -> Vt fp16 (+col bias)
// MODE 2: energy   A=Q[b,h](512x1024 ld4096) B=K[b,h]           -> E fp32
// MODE 3: PV       A=P[bh](512x512)          B=Vt[b,h](1024x512)-> out = gamma*acc + x
template<int MODE>
__global__ __launch_bounds__(256) void gemm_k(
    const f16* __restrict__ Aroot, const f16* __restrict__ Broot,
    void* __restrict__ out0, void* __restrict__ out1,
    const float* __restrict__ bias0, const float* __restrict__ bias1,
    const float* __restrict__ xin, const float* __restrict__ gam)
{
  constexpr int K   = (MODE==2) ? 1024 : 512;
  constexpr int LDA = (MODE==2) ? 4096 : 512;
  constexpr int LDB = (MODE==2) ? 4096 : 512;
  constexpr int NT  = K/32;
  constexpr int GX  = (MODE==0)?32 : (MODE==1)?4 : (MODE==2)?4 : 8;
  constexpr int GY  = (MODE==0)?8  : (MODE==1)?32: 4;
  constexpr int GZ  = (MODE==0||MODE==1)?32 : 128;
  constexpr int NWG = GX*GY*GZ;   // all %8 == 0

  // bijective XCD swizzle (T1, m204): contiguous flat-id chunk per XCD
  int flat = blockIdx.x + GX*(blockIdx.y + GY*blockIdx.z);
  flat = (flat & 7)*(NWG/8) + (flat >> 3);
  const int bx = flat % GX;  const int rem = flat / GX;
  const int by = rem % GY;   const int z  = rem / GY;

  const int t  = threadIdx.x;
  const int m0 = by*128, n0 = bx*128;

  const f16* Ap; const f16* Bp;
  if constexpr (MODE==0)      { Ap = Aroot;                    Bp = Broot + (size_t)z*PERB; }
  else if constexpr (MODE==1) { Ap = Aroot + (size_t)z*PERB;   Bp = Broot; }
  else if constexpr (MODE==2) { const int b=z>>2, h=z&3;
                                Ap = Aroot + (size_t)b*PERB + h*1024;
                                Bp = Broot + (size_t)b*PERB + h*1024; }
  else                        { const int b=z>>2, h=z&3;
                                Ap = Aroot + (size_t)z*EPB;
                                Bp = Broot + (size_t)b*PERB + (size_t)h*1024*512; }

  __shared__ f16 sA[128*32];
  __shared__ f16 sB[128*32];

  const int wv = t>>6, lane = t&63;
  // staging geometry: wave wv owns rows [wv*32, wv*32+32) of sA and sB.
  // Each gload16 stages 16 rows x 64B = 1KB linearly (lane i -> row base+i/4, 16B chunk i%4).
  const int srow = lane>>2, scol = (lane&3)*8;
  f16* sA0 = sA + (wv*32)*32;      // wave-uniform LDS bases
  f16* sA1 = sA + (wv*32+16)*32;
  f16* sB0 = sB + (wv*32)*32;
  f16* sB1 = sB + (wv*32+16)*32;
  const f16* gA0 = Ap + (size_t)(m0 + wv*32 + srow)*LDA + scol;
  const f16* gA1 = gA0 + (size_t)16*LDA;
  const f16* gB0 = Bp + (size_t)(n0 + wv*32 + srow)*LDB + scol;
  const f16* gB1 = gB0 + (size_t)16*LDB;

  const f32x4 zero = {0.f,0.f,0.f,0.f};
  f32x4 acc[4][4];
  #pragma unroll
  for (int i=0;i<4;i++)
    #pragma unroll
    for (int j=0;j<4;j++) acc[i][j] = zero;

  const int wm = (wv>>1)*64, wn = (wv&1)*64;
  const int lrow = lane&15, lk = (lane>>4)*8;

  for (int ks=0; ks<NT; ++ks) {
    if (ks) __syncthreads();             // previous tile's consumers done
    const int ko = ks*32;
    gload16(gA0 + ko, sA0);
    gload16(gA1 + ko, sA1);
    gload16(gB0 + ko, sB0);
    gload16(gB1 + ko, sB1);
    __syncthreads();                     // drains vmcnt(0): staged data visible
    f16x8 af[4], bf[4];
    #pragma unroll
    for (int i=0;i<4;i++) af[i] = *(const f16x8*)&sA[(wm + i*16 + lrow)*32 + lk];
    #pragma unroll
    for (int j=0;j<4;j++) bf[j] = *(const f16x8*)&sB[(wn + j*16 + lrow)*32 + lk];
    #pragma unroll
    for (int i=0;i<4;i++)
      #pragma unroll
      for (int j=0;j<4;j++)
        acc[i][j] = __builtin_amdgcn_mfma_f32_16x16x32_f16(af[i], bf[j], acc[i][j], 0,0,0);
  }

  // C/D layout (m89-verified): col = lane&15, row = (lane>>4)*4 + reg
  const int rbase = m0 + wm + (lane>>4)*4;
  #pragma unroll
  for (int i=0;i<4;i++) {
    const int row = rbase + i*16;
    #pragma unroll
    for (int j=0;j<4;j++) {
      const int col = n0 + wn + j*16 + lrow;
      f32x4 v = acc[i][j];
      #pragma unroll
      for (int r=0;r<4;r++) {
        const int rr = row + r;
        if constexpr (MODE==0) {
          if (rr < 512)
            ((f16*)out0)[(size_t)z*PERB + (size_t)rr*HWSZ + col]        = (f16)(v[r] + bias0[rr]);
          else
            ((f16*)out1)[(size_t)z*PERB + (size_t)(rr-512)*HWSZ + col]  = (f16)(v[r] + bias1[rr-512]);
        } else if constexpr (MODE==1) {
          ((f16*)out0)[(size_t)z*PERB + (size_t)rr*CCH + col] = (f16)(v[r] + bias0[col]);
        } else if constexpr (MODE==2) {
          ((float*)out0)[(size_t)z*EPB + (size_t)rr*CCH + col] = v[r];
        } else {
          const int b = z>>2, h = z&3;
          const size_t idx = (size_t)b*PERB + (size_t)rr*HWSZ + h*1024 + col;
          ((float*)out0)[idx] = gam[0]*v[r] + xin[idx];
        }
      }
    }
  }
}

extern "C" void kernel_launch(void* const* d_in, const int* in_sizes, int n_in,
                              void* d_out, int out_size, void* d_ws, size_t ws_size,
                              hipStream_t stream)
{
  const float* x  = (const float*)d_in[0];
  const float* Wq = (const float*)d_in[1];
  const float* bq = (const float*)d_in[2];
  const float* Wk = (const float*)d_in[3];
  const float* bk = (const float*)d_in[4];
  const float* Wv = (const float*)d_in[5];
  const float* bv = (const float*)d_in[6];
  const float* gm = (const float*)d_in[7];

  // ws layout (~258 MiB): Qb[134M] | Kb[134M] | Wqk[1M] | Wvh[0.5M]
  // aliases by lifetime: P -> Qb (Q dead after energy); Vt -> Kb (K dead after energy)
  char* ws  = (char*)d_ws;
  f16* Qb   = (f16*)ws;
  f16* Kb   = (f16*)(ws + 134217728ull);
  f16* Wqk  = (f16*)(ws + 268435456ull);
  f16* Wvh  = Wqk + 1024*512;
  f16* Pb   = Qb;
  f16* Vt   = Kb;
  // d_out doubles as scratch until the final PV epilogue overwrites all of it:
  float* E  = (float*)d_out;                              // [0, 134M)  energy fp32
  f16*  Xt  = (f16*)((char*)d_out + 134217728ull);        // [134M,268M) x^T fp16
  float* out = (float*)d_out;

  wconv_k    <<<256, 256, 0, stream>>>(Wq, Wk, Wv, Wqk, Wvh);
  transpose_k<<<dim3(64,8,32),  256, 0, stream>>>(x, Xt);
  gemm_k<0>  <<<dim3(32,8,32),  256, 0, stream>>>(Wqk, Xt, Qb, Kb, bq, bk, nullptr, nullptr);
  gemm_k<2>  <<<dim3(4,4,128),  256, 0, stream>>>(Qb, Kb, E, nullptr, nullptr, nullptr, nullptr, nullptr);
  gemm_k<1>  <<<dim3(4,32,32),  256, 0, stream>>>(Xt, Wvh, Vt, nullptr, bv, nullptr, nullptr, nullptr);
  softmax_k  <<<16384, 256, 0, stream>>>(E, Pb);
  gemm_k<3>  <<<dim3(8,4,128),  256, 0, stream>>>(Pb, Vt, out, nullptr, nullptr, nullptr, x, gm);
}